// Round 1
// baseline (1504.260 us; speedup 1.0000x reference)
//
#include <hip/hip_runtime.h>
#include <hip/hip_bf16.h>

// MultiLoRALinear: out[b,s,o] = x@W.T + bias + (x @ A[idx[b]]) @ B[idx[b]]
// M = 8*2048 = 16384, K = 4096, N = 4096, rank 16, ALPHA = 1.
//
// Pipeline (all per-call, deterministic):
//   1) cvt_bf16: x (fp32->bf16), W (fp32->bf16) into d_ws
//   2) lora_inter: inter[m][r] = sum_d x[m][d]*A[slot(m)][d][r]  (fp32)
//   3) gemm_fused: bf16 MFMA 128x128-tile GEMM (m97 structure) with
//      epilogue out = acc + bias + inter @ B[slot]

#define M_TOT 16384
#define K_TOT 4096
#define N_TOT 4096
#define RANK 16

typedef __attribute__((ext_vector_type(8))) short bf16x8;
typedef __attribute__((ext_vector_type(4))) float f32x4;

// ---------------- fp32 -> bf16 (round-to-nearest-even) ----------------
__device__ __forceinline__ unsigned short f2bf(float f) {
  unsigned int u = __builtin_bit_cast(unsigned int, f);
  u += 0x7fffu + ((u >> 16) & 1u);
  return (unsigned short)(u >> 16);
}

__global__ void cvt_bf16_kernel(const float* __restrict__ src,
                                unsigned short* __restrict__ dst, int n4) {
  int i = blockIdx.x * blockDim.x + threadIdx.x;
  const int stride = gridDim.x * blockDim.x;
  for (; i < n4; i += stride) {
    const float4 v = reinterpret_cast<const float4*>(src)[i];
    ushort4 o;
    o.x = f2bf(v.x); o.y = f2bf(v.y); o.z = f2bf(v.z); o.w = f2bf(v.w);
    reinterpret_cast<ushort4*>(dst)[i] = o;
  }
}

// ---------------- inter = x @ A[slot]  (one wave per row m) ----------------
__global__ void lora_inter_kernel(const float* __restrict__ x,
                                  const float* __restrict__ loraA,
                                  const int* __restrict__ idx,
                                  float* __restrict__ inter) {
  const int lane = threadIdx.x & 63;
  const int wv = threadIdx.x >> 6;
  const int m = blockIdx.x * 4 + wv;          // grid = 4096 blocks of 256
  const int slot = idx[m >> 11];              // batch = m / 2048
  const float* __restrict__ A = loraA + (size_t)slot * K_TOT * RANK;
  const float* __restrict__ xr = x + (size_t)m * K_TOT;

  float acc[RANK];
#pragma unroll
  for (int r = 0; r < RANK; ++r) acc[r] = 0.f;

  for (int d0 = 0; d0 < K_TOT; d0 += 64) {
    const float xv = xr[d0 + lane];
    const float4* Ar = reinterpret_cast<const float4*>(A + (size_t)(d0 + lane) * RANK);
    const float4 a0 = Ar[0], a1 = Ar[1], a2 = Ar[2], a3 = Ar[3];
    acc[0]  += xv * a0.x;  acc[1]  += xv * a0.y;  acc[2]  += xv * a0.z;  acc[3]  += xv * a0.w;
    acc[4]  += xv * a1.x;  acc[5]  += xv * a1.y;  acc[6]  += xv * a1.z;  acc[7]  += xv * a1.w;
    acc[8]  += xv * a2.x;  acc[9]  += xv * a2.y;  acc[10] += xv * a2.z;  acc[11] += xv * a2.w;
    acc[12] += xv * a3.x;  acc[13] += xv * a3.y;  acc[14] += xv * a3.z;  acc[15] += xv * a3.w;
  }
#pragma unroll
  for (int r = 0; r < RANK; ++r) {
    float v = acc[r];
#pragma unroll
    for (int off = 32; off; off >>= 1) v += __shfl_xor(v, off);
    acc[r] = v;
  }
  if (lane == 0) {
    float4* op = reinterpret_cast<float4*>(inter + (size_t)m * RANK);
    op[0] = make_float4(acc[0], acc[1], acc[2], acc[3]);
    op[1] = make_float4(acc[4], acc[5], acc[6], acc[7]);
    op[2] = make_float4(acc[8], acc[9], acc[10], acc[11]);
    op[3] = make_float4(acc[12], acc[13], acc[14], acc[15]);
  }
}

// ---------------- fused GEMM ----------------
// 128x128 tile, BK=64, 4 waves (2x2), 4x4 fragments of 16x16x32 per wave.
#define BM 128
#define BN 128
#define BK 64

__device__ __forceinline__ void gload16(const void* g, void* l) {
  __builtin_amdgcn_global_load_lds(
      (const __attribute__((address_space(1))) unsigned int*)g,
      (__attribute__((address_space(3))) unsigned int*)l, 16, 0, 0);
}

__global__ __launch_bounds__(256, 2) void gemm_fused_kernel(
    const unsigned short* __restrict__ xb,   // [M_TOT][K] bf16
    const unsigned short* __restrict__ wb,   // [N_TOT][K] bf16
    const float* __restrict__ bias,          // [N]
    const float* __restrict__ inter,         // [M_TOT][RANK] fp32
    const float* __restrict__ loraB,         // [32][RANK][N] fp32
    const int* __restrict__ idx,             // [8]
    float* __restrict__ out) {               // [M_TOT][N] fp32
  __shared__ unsigned short As[BM * BK];     // 16 KiB
  __shared__ unsigned short Bs[BN * BK];     // 16 KiB

  const int tid = threadIdx.x;
  const int lane = tid & 63;
  const int wv = tid >> 6;
  const int wr = wv >> 1, wc = wv & 1;       // 2x2 wave grid

  const int bid = blockIdx.x;
  const int bm = bid >> 5;                   // 0..127
  const int bn = bid & 31;                   // 0..31
  const int m0 = bm * BM;
  const int n0 = bn * BN;

  f32x4 acc[4][4];
#pragma unroll
  for (int i = 0; i < 4; ++i)
#pragma unroll
    for (int j = 0; j < 4; ++j) acc[i][j] = (f32x4){0.f, 0.f, 0.f, 0.f};

  // staging descriptors: 1024 chunks of 16B per tile (128 rows x 128B)
  const unsigned short* gA[4];
  const unsigned short* gB[4];
  int loff[4];
#pragma unroll
  for (int i = 0; i < 4; ++i) {
    const int c = (wv * 4 + i) * 64 + lane;  // 0..1023
    const int row = c >> 3;
    const int col = (c & 7) << 3;            // bf16 elements within row
    gA[i] = xb + (size_t)(m0 + row) * K_TOT + col;
    gB[i] = wb + (size_t)(n0 + row) * K_TOT + col;
    loff[i] = (wv * 4 + i) * 512;            // wave-uniform LDS base (elements)
  }

  // LDS fragment read bases
  const unsigned short* arp[4];
  const unsigned short* brp[4];
#pragma unroll
  for (int i = 0; i < 4; ++i) {
    arp[i] = As + (wr * 64 + i * 16 + (lane & 15)) * BK + ((lane >> 4) << 3);
    brp[i] = Bs + (wc * 64 + i * 16 + (lane & 15)) * BK + ((lane >> 4) << 3);
  }

  for (int kt = 0; kt < K_TOT; kt += BK) {
#pragma unroll
    for (int i = 0; i < 4; ++i) {
      gload16(gA[i] + kt, As + loff[i]);
      gload16(gB[i] + kt, Bs + loff[i]);
    }
    __syncthreads();  // emits vmcnt(0): staged data visible

#pragma unroll
    for (int kk = 0; kk < BK; kk += 32) {
      bf16x8 af[4], bfr[4];
#pragma unroll
      for (int mi = 0; mi < 4; ++mi)
        af[mi] = *reinterpret_cast<const bf16x8*>(arp[mi] + kk);
#pragma unroll
      for (int ni = 0; ni < 4; ++ni)
        bfr[ni] = *reinterpret_cast<const bf16x8*>(brp[ni] + kk);
#pragma unroll
      for (int mi = 0; mi < 4; ++mi)
#pragma unroll
        for (int ni = 0; ni < 4; ++ni)
          acc[mi][ni] = __builtin_amdgcn_mfma_f32_16x16x32_bf16(
              af[mi], bfr[ni], acc[mi][ni], 0, 0, 0);
    }
    __syncthreads();  // all waves done reading before next stage
  }

  // ---------------- epilogue: + bias + inter @ B[slot] ----------------
  const int slot = idx[m0 >> 11];            // uniform per block (128 | 2048)
  const float* __restrict__ Bmat = loraB + (size_t)slot * RANK * N_TOT;

#pragma unroll
  for (int ni = 0; ni < 4; ++ni) {
    const int gn = n0 + wc * 64 + ni * 16 + (lane & 15);
    const float bv = bias[gn];
    float bc[RANK];
#pragma unroll
    for (int q = 0; q < RANK; ++q) bc[q] = Bmat[q * N_TOT + gn];
#pragma unroll
    for (int mi = 0; mi < 4; ++mi) {
      const int gmb = m0 + wr * 64 + mi * 16 + ((lane >> 4) << 2);
#pragma unroll
      for (int r = 0; r < 4; ++r) {
        const int gm = gmb + r;
        const float* __restrict__ iv = inter + (size_t)gm * RANK;
        float lora = 0.f;
#pragma unroll
        for (int q = 0; q < RANK; ++q) lora += iv[q] * bc[q];
        out[(size_t)gm * N_TOT + gn] = acc[mi][ni][r] + bv + lora;
      }
    }
  }
}

// ---------------- host launcher ----------------
extern "C" void kernel_launch(void* const* d_in, const int* in_sizes, int n_in,
                              void* d_out, int out_size, void* d_ws, size_t ws_size,
                              hipStream_t stream) {
  const float* x     = (const float*)d_in[0];  // [8,2048,4096]
  const float* w     = (const float*)d_in[1];  // [4096,4096]
  const float* bias  = (const float*)d_in[2];  // [4096]
  const float* loraA = (const float*)d_in[3];  // [32,4096,16]
  const float* loraB = (const float*)d_in[4];  // [32,16,4096]
  const int*   idx   = (const int*)d_in[5];    // [8]
  float* out = (float*)d_out;

  char* ws = (char*)d_ws;
  unsigned short* xb = (unsigned short*)ws;                       // 134,217,728 B
  unsigned short* wbuf = (unsigned short*)(ws + 134217728);       //  33,554,432 B
  float* inter = (float*)(ws + 134217728 + 33554432);             //   1,048,576 B

  cvt_bf16_kernel<<<2048, 256, 0, stream>>>(x, xb, M_TOT * K_TOT / 4);
  cvt_bf16_kernel<<<1024, 256, 0, stream>>>(w, wbuf, N_TOT * K_TOT / 4);
  lora_inter_kernel<<<M_TOT / 4, 256, 0, stream>>>(x, loraA, idx, inter);
  gemm_fused_kernel<<<(M_TOT / BM) * (N_TOT / BN), 256, 0, stream>>>(
      xb, wbuf, bias, inter, loraB, idx, out);
}